// Round 4
// baseline (143.408 us; speedup 1.0000x reference)
//
#include <hip/hip_runtime.h>

typedef float floatx4 __attribute__((ext_vector_type(4)));

// Per-row semantics (row = 9 floats = x[3][3]):
//   mi[j]  = ties ? 0 : (1 - argmax(x[j]))        in {1,0,-1}
//   calc   = |mi[1]| * (mi[0]+mi[1]+mi[2])
//   keep[j]= sign(mi[j]) == sign(calc)  (0 matches 0)
//   idx    = calc==0 ? 1 : (calc>=1 ? 0 : 2)
//   vals[j]= keep[j] ? x[j][idx] : 0
//   win    = first-occurrence argmax(vals)
//   out    = keep[win] ? x[win][:] : 0,0,0

__device__ __forceinline__ void compute_row(
    float v00, float v01, float v02,
    float v10, float v11, float v12,
    float v20, float v21, float v22,
    float& o0, float& o1, float& o2) {

    float v[3][3] = {{v00, v01, v02}, {v10, v11, v12}, {v20, v21, v22}};

    int mi[3];
#pragma unroll
    for (int j = 0; j < 3; ++j) {
        const float a = v[j][0], b = v[j][1], c = v[j][2];
        const float m = fmaxf(a, fmaxf(b, c));
        const int ties = (int)(a == m) + (int)(b == m) + (int)(c == m);
        int am;
        if (a == m) am = 0;
        else if (b == m) am = 1;
        else am = 2;
        mi[j] = (ties > 1) ? 0 : (1 - am);
    }

    const int calc = (mi[1] < 0 ? -mi[1] : mi[1]) * (mi[0] + mi[1] + mi[2]);

    bool keep[3];
#pragma unroll
    for (int j = 0; j < 3; ++j)
        keep[j] = (calc > 0 && mi[j] > 0) ||
                  (calc < 0 && mi[j] < 0) ||
                  (calc == 0 && mi[j] == 0);

    const int idx = (calc == 0) ? 1 : ((calc >= 1) ? 0 : 2);

    float vals[3];
#pragma unroll
    for (int j = 0; j < 3; ++j) {
        const float vj = (idx == 0) ? v[j][0] : ((idx == 2) ? v[j][2] : v[j][1]);
        vals[j] = keep[j] ? vj : 0.0f;
    }

    const bool w1 = vals[1] > vals[0];
    const float b01 = w1 ? vals[1] : vals[0];
    const bool w2 = vals[2] > b01;

    const bool keepw = w2 ? keep[2] : (w1 ? keep[1] : keep[0]);

    const float r0 = w2 ? v[2][0] : (w1 ? v[1][0] : v[0][0]);
    const float r1 = w2 ? v[2][1] : (w1 ? v[1][1] : v[0][1]);
    const float r2 = w2 ? v[2][2] : (w1 ? v[1][2] : v[0][2]);

    o0 = keepw ? r0 : 0.0f;
    o1 = keepw ? r1 : 0.0f;
    o2 = keepw ? r2 : 0.0f;
}

// 8 rows per thread: 18 float4 loads (all issued before compute), 6 nt stores.
__global__ __launch_bounds__(256) void pick_rows_kernel(
    const float* __restrict__ in, float* __restrict__ out, long long nrows) {

    const long long t = (long long)blockIdx.x * blockDim.x + threadIdx.x;
    const long long r0 = t * 8;
    if (r0 >= nrows) return;

    if (r0 + 8 <= nrows) {
        // 8 rows = 72 floats = 18 float4, 16B-aligned (byte offset 288*t)
        const float4* p4 = reinterpret_cast<const float4*>(in + r0 * 9);
        float4 f[18];
#pragma unroll
        for (int i = 0; i < 18; ++i) f[i] = p4[i];   // 18 loads in flight

        float x[72];
#pragma unroll
        for (int i = 0; i < 18; ++i) {
            x[i * 4 + 0] = f[i].x;
            x[i * 4 + 1] = f[i].y;
            x[i * 4 + 2] = f[i].z;
            x[i * 4 + 3] = f[i].w;
        }

        float o[24];
#pragma unroll
        for (int j = 0; j < 8; ++j) {
            compute_row(x[j * 9 + 0], x[j * 9 + 1], x[j * 9 + 2],
                        x[j * 9 + 3], x[j * 9 + 4], x[j * 9 + 5],
                        x[j * 9 + 6], x[j * 9 + 7], x[j * 9 + 8],
                        o[j * 3 + 0], o[j * 3 + 1], o[j * 3 + 2]);
        }

        // 24 floats = 6 float4, 16B-aligned (byte offset 96*t), nontemporal
        floatx4* q4 = reinterpret_cast<floatx4*>(out + r0 * 3);
#pragma unroll
        for (int i = 0; i < 6; ++i) {
            floatx4 q;
            q.x = o[i * 4 + 0];
            q.y = o[i * 4 + 1];
            q.z = o[i * 4 + 2];
            q.w = o[i * 4 + 3];
            __builtin_nontemporal_store(q, q4 + i);
        }
    } else {
        // scalar tail (rows not a multiple of 8)
        for (long long r = r0; r < nrows; ++r) {
            const float* p = in + r * 9;
            float o0, o1, o2;
            compute_row(p[0], p[1], p[2], p[3], p[4], p[5], p[6], p[7], p[8],
                        o0, o1, o2);
            out[r * 3 + 0] = o0;
            out[r * 3 + 1] = o1;
            out[r * 3 + 2] = o2;
        }
    }
}

extern "C" void kernel_launch(void* const* d_in, const int* in_sizes, int n_in,
                              void* d_out, int out_size, void* d_ws, size_t ws_size,
                              hipStream_t stream) {
    const float* in = (const float*)d_in[0];
    float* out = (float*)d_out;
    const long long nrows = (long long)in_sizes[0] / 9;

    const long long nthreads = (nrows + 7) / 8;
    const int block = 256;
    const long long nblocks = (nthreads + block - 1) / block;
    pick_rows_kernel<<<(int)nblocks, block, 0, stream>>>(in, out, nrows);
}

// Round 5
// 70.257 us; speedup vs baseline: 2.0412x; 2.0412x over previous
//
#include <hip/hip_runtime.h>

typedef float floatx4 __attribute__((ext_vector_type(4)));

#define ROWS_PER_BLOCK 256
#define BLOCK_THREADS 256

// Per-row semantics (row = 9 floats = x[3][3]):
//   mi[j]  = ties ? 0 : (1 - argmax(x[j]))        in {1,0,-1}
//   calc   = |mi[1]| * (mi[0]+mi[1]+mi[2])
//   keep[j]= sign(mi[j]) == sign(calc)  (0 matches 0)
//   idx    = calc==0 ? 1 : (calc>=1 ? 0 : 2)
//   vals[j]= keep[j] ? x[j][idx] : 0
//   win    = first-occurrence argmax(vals)
//   out    = keep[win] ? x[win][:] : 0,0,0

__device__ __forceinline__ void compute_row(
    const float v[3][3], float& o0, float& o1, float& o2) {

    int mi[3];
#pragma unroll
    for (int j = 0; j < 3; ++j) {
        const float a = v[j][0], b = v[j][1], c = v[j][2];
        const float m = fmaxf(a, fmaxf(b, c));
        const int ties = (int)(a == m) + (int)(b == m) + (int)(c == m);
        int am;
        if (a == m) am = 0;
        else if (b == m) am = 1;
        else am = 2;
        mi[j] = (ties > 1) ? 0 : (1 - am);
    }

    const int calc = (mi[1] < 0 ? -mi[1] : mi[1]) * (mi[0] + mi[1] + mi[2]);

    bool keep[3];
#pragma unroll
    for (int j = 0; j < 3; ++j)
        keep[j] = (calc > 0 && mi[j] > 0) ||
                  (calc < 0 && mi[j] < 0) ||
                  (calc == 0 && mi[j] == 0);

    const int idx = (calc == 0) ? 1 : ((calc >= 1) ? 0 : 2);

    float vals[3];
#pragma unroll
    for (int j = 0; j < 3; ++j) {
        const float vj = (idx == 0) ? v[j][0] : ((idx == 2) ? v[j][2] : v[j][1]);
        vals[j] = keep[j] ? vj : 0.0f;
    }

    const bool w1 = vals[1] > vals[0];
    const float b01 = w1 ? vals[1] : vals[0];
    const bool w2 = vals[2] > b01;

    const bool keepw = w2 ? keep[2] : (w1 ? keep[1] : keep[0]);

    const float r0 = w2 ? v[2][0] : (w1 ? v[1][0] : v[0][0]);
    const float r1 = w2 ? v[2][1] : (w1 ? v[1][1] : v[0][1]);
    const float r2 = w2 ? v[2][2] : (w1 ? v[1][2] : v[0][2]);

    o0 = keepw ? r0 : 0.0f;
    o1 = keepw ? r1 : 0.0f;
    o2 = keepw ? r2 : 0.0f;
}

__global__ __launch_bounds__(BLOCK_THREADS) void pick_rows_kernel(
    const float* __restrict__ in, float* __restrict__ out, long long nrows) {

    __shared__ float lds_in[ROWS_PER_BLOCK * 9];  // 9216 B

    const int tid = threadIdx.x;
    const long long tileStride = (long long)gridDim.x * ROWS_PER_BLOCK;

    for (long long rowBase = (long long)blockIdx.x * ROWS_PER_BLOCK;
         rowBase < nrows; rowBase += tileStride) {

        const long long rowsLeft = nrows - rowBase;
        const int rowsHere = rowsLeft < ROWS_PER_BLOCK ? (int)rowsLeft : ROWS_PER_BLOCK;

        // ---- stage input tile into LDS: 576 coalesced nontemporal float4 ----
        if (rowsHere == ROWS_PER_BLOCK) {
            const floatx4* src4 = reinterpret_cast<const floatx4*>(in + rowBase * 9);
            {
                floatx4 v0 = __builtin_nontemporal_load(src4 + tid);
                floatx4 v1 = __builtin_nontemporal_load(src4 + tid + 256);
                lds_in[tid * 4 + 0] = v0.x;
                lds_in[tid * 4 + 1] = v0.y;
                lds_in[tid * 4 + 2] = v0.z;
                lds_in[tid * 4 + 3] = v0.w;
                lds_in[(tid + 256) * 4 + 0] = v1.x;
                lds_in[(tid + 256) * 4 + 1] = v1.y;
                lds_in[(tid + 256) * 4 + 2] = v1.z;
                lds_in[(tid + 256) * 4 + 3] = v1.w;
                if (tid < 64) {
                    floatx4 v2 = __builtin_nontemporal_load(src4 + tid + 512);
                    lds_in[(tid + 512) * 4 + 0] = v2.x;
                    lds_in[(tid + 512) * 4 + 1] = v2.y;
                    lds_in[(tid + 512) * 4 + 2] = v2.z;
                    lds_in[(tid + 512) * 4 + 3] = v2.w;
                }
            }
        } else {
            const float* src = in + rowBase * 9;
            const int nf = rowsHere * 9;
            for (int k = tid; k < nf; k += BLOCK_THREADS) lds_in[k] = src[k];
        }
        __syncthreads();

        // ---- per-row compute + direct packed store ----
        if (tid < rowsHere) {
            float v[3][3];
#pragma unroll
            for (int j = 0; j < 3; ++j)
#pragma unroll
                for (int k = 0; k < 3; ++k)
                    v[j][k] = lds_in[tid * 9 + j * 3 + k];

            float o0, o1, o2;
            compute_row(v, o0, o1, o2);

            // lane-stride 12 B, contiguous coverage across the wave;
            // L2 write-back merges into full 64 B lines.
            float* dst = out + (rowBase + tid) * 3;
            dst[0] = o0;
            dst[1] = o1;
            dst[2] = o2;
        }
        __syncthreads();  // protect lds_in before next tile's staging
    }
}

extern "C" void kernel_launch(void* const* d_in, const int* in_sizes, int n_in,
                              void* d_out, int out_size, void* d_ws, size_t ws_size,
                              hipStream_t stream) {
    const float* in = (const float*)d_in[0];
    float* out = (float*)d_out;
    const long long nrows = (long long)in_sizes[0] / 9;

    const long long tiles = (nrows + ROWS_PER_BLOCK - 1) / ROWS_PER_BLOCK;
    int grid = (int)(tiles < 2048 ? tiles : 2048);
    pick_rows_kernel<<<grid, BLOCK_THREADS, 0, stream>>>(in, out, nrows);
}